// Round 8
// baseline (443.925 us; speedup 1.0000x reference)
//
#include <hip/hip_runtime.h>
#include <cstddef>
#include <cstdint>

#define B_   128
#define L_   31
#define D_   1024
#define DI_  2048
#define DS_  16
#define DC_  5
#define DTR_ 64
#define ROWS (B_ * L_)   // 3968
#define MPAD 4096        // padded M for 256-tile GEMMs
#define KCLS (L_ * D_)   // 31744

// weight-buffer offsets (u16 elements)
#define W_IN  0          // 4096x1024
#define W_OUT 4194304    // 1024x2048
#define W_F1  6291456    // 2048x1024
#define W_F2  8388608    // 1024x2048
#define W_XP  10485760   // 128x2048 (rows 96..127 zero)
#define W_DT  10747904   // 2048x64
#define WTOT  10878976

typedef unsigned short u16;
typedef __attribute__((ext_vector_type(8))) short s16x8;
typedef __attribute__((ext_vector_type(4))) float f32x4;

__device__ __forceinline__ float silu_f(float x) { return x / (1.0f + __expf(-x)); }

__device__ __forceinline__ u16 f2b(float f) {
    union { float f; uint32_t u; } c; c.f = f;
    uint32_t u = c.u + 0x7FFF + ((c.u >> 16) & 1);
    return (u16)(u >> 16);
}
__device__ __forceinline__ float b2f(u16 b) {
    union { uint32_t u; float f; } c; c.u = ((uint32_t)b) << 16;
    return c.f;
}
__device__ __forceinline__ uint32_t pack2(float lo, float hi) {
    return (uint32_t)f2b(lo) | ((uint32_t)f2b(hi) << 16);
}
__device__ __forceinline__ void cvt8(const float* __restrict__ s, u16* __restrict__ d) {
    const float4* p = (const float4*)s;
    float4 a = p[0], b = p[1];
    uint4 r;
    r.x = pack2(a.x, a.y); r.y = pack2(a.z, a.w);
    r.z = pack2(b.x, b.y); r.w = pack2(b.z, b.w);
    *(uint4*)d = r;
}

#define GLD16(g, s) __builtin_amdgcn_global_load_lds( \
    (const __attribute__((address_space(1))) void*)(g), \
    (__attribute__((address_space(3))) void*)(s), 16, 0, 0)

// ---------------- all-weights fp32 -> bf16 (single launch) ----------------
__global__ __launch_bounds__(256) void f2b_all_kernel(
    const float* __restrict__ inW, const float* __restrict__ outW,
    const float* __restrict__ f1W, const float* __restrict__ f2W,
    const float* __restrict__ xpW, const float* __restrict__ dtW,
    u16* __restrict__ wbuf)
{
    int g = blockIdx.x * 256 + threadIdx.x;
    if (g < 524288) { cvt8(inW + (size_t)g * 8, wbuf + W_IN + (size_t)g * 8); return; }
    g -= 524288;
    if (g < 262144) { cvt8(outW + (size_t)g * 8, wbuf + W_OUT + (size_t)g * 8); return; }
    g -= 262144;
    if (g < 262144) { cvt8(f1W + (size_t)g * 8, wbuf + W_F1 + (size_t)g * 8); return; }
    g -= 262144;
    if (g < 262144) { cvt8(f2W + (size_t)g * 8, wbuf + W_F2 + (size_t)g * 8); return; }
    g -= 262144;
    if (g < 32768) {   // x_proj, padded 96 -> 128 rows
        const int row = g >> 8, col8 = (g & 255) * 8;
        u16* d = wbuf + W_XP + (size_t)row * 2048 + col8;
        if (row < 96) cvt8(xpW + (size_t)row * 2048 + col8, d);
        else *(uint4*)d = make_uint4(0, 0, 0, 0);
        return;
    }
    g -= 32768;
    if (g < 16384) cvt8(dtW + (size_t)g * 8, wbuf + W_DT + (size_t)g * 8);
}

// ---------------- LayerNorm (one block per row, D=1024) -> bf16 out ----------------
__global__ __launch_bounds__(256) void ln_kernel(const float* __restrict__ x,
                                                 const float* __restrict__ w,
                                                 const float* __restrict__ b,
                                                 u16* __restrict__ y)
{
    const int row = blockIdx.x;
    const float* xr = x + (size_t)row * D_;
    float v[4];
    float sum = 0.f, sq = 0.f;
#pragma unroll
    for (int i = 0; i < 4; i++) {
        v[i] = xr[threadIdx.x + i * 256];
        sum += v[i];
        sq  += v[i] * v[i];
    }
#pragma unroll
    for (int o = 32; o > 0; o >>= 1) {
        sum += __shfl_down(sum, o, 64);
        sq  += __shfl_down(sq, o, 64);
    }
    __shared__ float red[8];
    const int wid = threadIdx.x >> 6;
    if ((threadIdx.x & 63) == 0) { red[wid] = sum; red[4 + wid] = sq; }
    __syncthreads();
    sum = red[0] + red[1] + red[2] + red[3];
    sq  = red[4] + red[5] + red[6] + red[7];
    const float mean = sum * (1.0f / D_);
    const float var  = sq * (1.0f / D_) - mean * mean;
    const float rstd = rsqrtf(var + 1e-5f);
    u16* yr = y + (size_t)row * D_;
#pragma unroll
    for (int i = 0; i < 4; i++) {
        const int c = threadIdx.x + i * 256;
        yr[c] = f2b((v[i] - mean) * rstd * w[c] + b[c]);
    }
}

// ---------------- fused: x2 = x + p0+p1+p2+p3; h2 = LN(x2) -> bf16 ----------------
__global__ __launch_bounds__(256) void ln2_fuse_kernel(const float* __restrict__ x,
                                                       const float* __restrict__ pq,
                                                       const float* __restrict__ w,
                                                       const float* __restrict__ b,
                                                       float* __restrict__ x2,
                                                       u16* __restrict__ y)
{
    const int row = blockIdx.x;
    const size_t base = (size_t)row * D_;
    const size_t PS = (size_t)ROWS * D_;
    float v[4];
    float sum = 0.f, sq = 0.f;
#pragma unroll
    for (int i = 0; i < 4; i++) {
        const int c = threadIdx.x + i * 256;
        float s = x[base + c];
        s += pq[base + c];
        s += pq[PS + base + c];
        s += pq[2 * PS + base + c];
        s += pq[3 * PS + base + c];
        x2[base + c] = s;
        v[i] = s;
        sum += s;
        sq  += s * s;
    }
#pragma unroll
    for (int o = 32; o > 0; o >>= 1) {
        sum += __shfl_down(sum, o, 64);
        sq  += __shfl_down(sq, o, 64);
    }
    __shared__ float red[8];
    const int wid = threadIdx.x >> 6;
    if ((threadIdx.x & 63) == 0) { red[wid] = sum; red[4 + wid] = sq; }
    __syncthreads();
    sum = red[0] + red[1] + red[2] + red[3];
    sq  = red[4] + red[5] + red[6] + red[7];
    const float mean = sum * (1.0f / D_);
    const float var  = sq * (1.0f / D_) - mean * mean;
    const float rstd = rsqrtf(var + 1e-5f);
    u16* yr = y + base;
#pragma unroll
    for (int i = 0; i < 4; i++) {
        const int c = threadIdx.x + i * 256;
        yr[c] = f2b((v[i] - mean) * rstd * w[c] + b[c]);
    }
}

// ---------------- x3 = x2 + q0+q1+q2+q3 + b2 (vectorized) ----------------
__global__ __launch_bounds__(256) void add4_bias_kernel(const float* __restrict__ x2,
                                                        const float* __restrict__ pq,
                                                        const float* __restrict__ b2,
                                                        float* __restrict__ x3)
{
    const int i = blockIdx.x * 256 + threadIdx.x;   // float4 index over ROWS*1024/4
    const size_t PS4 = (size_t)ROWS * D_ / 4;
    float4 a  = ((const float4*)x2)[i];
    float4 c0 = ((const float4*)pq)[i];
    float4 c1 = ((const float4*)pq)[PS4 + i];
    float4 c2 = ((const float4*)pq)[2 * PS4 + i];
    float4 c3 = ((const float4*)pq)[3 * PS4 + i];
    float4 bb = ((const float4*)b2)[i & 255];
    float4 r;
    r.x = a.x + c0.x + c1.x + c2.x + c3.x + bb.x;
    r.y = a.y + c0.y + c1.y + c2.y + c3.y + bb.y;
    r.z = a.z + c0.z + c1.z + c2.z + c3.z + bb.z;
    r.w = a.w + c0.w + c1.w + c2.w + c3.w + bb.w;
    ((float4*)x3)[i] = r;
}

// ================= 256x256-tile bf16 MFMA GEMM, BK=64, 8 waves =================
// T4 counted-vmcnt 2-deep pipeline (m218): raw s_barrier + asm vmcnt(8) so the
// next tile's 8 global_load_lds stay IN FLIGHT across the barrier (never drain
// to 0 mid-loop). T2 both-sides XOR swizzle (rule #21): linear LDS dest,
// pre-swizzled global source granule sg^(srow&7), same XOR on fragment reads.
// T5 setprio around the MFMA cluster.
// OUT: 1 = bf16 store, 3 = f32 partial (z-indexed). Stores guarded to row < ROWS.
template <int ACT, bool BIAS, int OUT>
__global__ __launch_bounds__(512, 2) void gemm256(
    const u16* __restrict__ A, const u16* __restrict__ W,
    const float* __restrict__ bias, void* __restrict__ Cout,
    int K, int Nout, int kLen)
{
    __shared__ __align__(16) u16 As[2][256 * 64];   // 2 x 32 KB
    __shared__ __align__(16) u16 Bs[2][256 * 64];   // 2 x 32 KB
    const int tid = threadIdx.x;
    const int l = tid & 63;
    const int w = tid >> 6, wr = w >> 2, wc = w & 3;
    const int lane15 = l & 15, lhi = l >> 4;
    const int key = lane15 & 7;                      // read-side swizzle key
    const int bm = blockIdx.y * 256, bn = blockIdx.x * 256;
    const int kOff = blockIdx.z * kLen;

    // staging: thread covers 16B; chunk c = rows [c*64, c*64+64)
    const int srow = tid >> 3;                       // 0..63 row within chunk
    const int sg   = tid & 7;                        // LDS granule (linear)
    const int sgx  = sg ^ (srow & 7);                // swizzled SOURCE granule
    const u16* gA = A + (size_t)(bm + srow) * K + kOff + sgx * 8;
    const u16* gB = W + (size_t)(bn + srow) * K + kOff + sgx * 8;
    const int soff = srow * 64 + sg * 8;             // == tid*8 (linear in tid)

    const int NT = kLen / 64;
    f32x4 acc[8][4] = {};

#define STAGE256(tt, bsel) do {                                             \
    const size_t go_ = (size_t)(tt) * 64;                                   \
    _Pragma("unroll")                                                       \
    for (int c_ = 0; c_ < 4; c_++) {                                        \
        GLD16(gA + (size_t)c_ * 64 * K + go_, &As[bsel][c_ * 4096 + soff]); \
        GLD16(gB + (size_t)c_ * 64 * K + go_, &Bs[bsel][c_ * 4096 + soff]); \
    }                                                                       \
} while (0)

    // prologue: stage tiles 0 and 1 (16 loads/thread outstanding)
    STAGE256(0, 0);
    if (NT > 1) STAGE256(1, 1);

    for (int t = 0; t < NT; t++) {
        const int cur = t & 1;
        // wait ONLY tile t's loads (t+1's 8 remain in flight across the barrier)
        if (t + 1 < NT) asm volatile("s_waitcnt vmcnt(8)" ::: "memory");
        else            asm volatile("s_waitcnt vmcnt(0)" ::: "memory");
        __builtin_amdgcn_s_barrier();                // tile t visible to all waves

        const u16* as = As[cur];
        const u16* bs = Bs[cur];
        s16x8 bf[2][4];
#pragma unroll
        for (int ks = 0; ks < 2; ks++)
#pragma unroll
            for (int ni = 0; ni < 4; ni++)
                bf[ks][ni] = *(const s16x8*)(bs + (wc * 64 + ni * 16 + lane15) * 64
                                                + (((ks * 4 + lhi) ^ key)) * 8);
        __builtin_amdgcn_s_setprio(1);
#pragma unroll
        for (int mh = 0; mh < 2; mh++) {
            s16x8 af[2][4];
#pragma unroll
            for (int ks = 0; ks < 2; ks++)
#pragma unroll
                for (int mi = 0; mi < 4; mi++)
                    af[ks][mi] = *(const s16x8*)(as + (wr * 128 + mh * 64 + mi * 16 + lane15) * 64
                                                    + (((ks * 4 + lhi) ^ key)) * 8);
#pragma unroll
            for (int ks = 0; ks < 2; ks++)
#pragma unroll
                for (int mi = 0; mi < 4; mi++)
#pragma unroll
                    for (int ni = 0; ni < 4; ni++)
                        acc[mh * 4 + mi][ni] = __builtin_amdgcn_mfma_f32_16x16x32_bf16(
                            af[ks][mi], bf[ks][ni], acc[mh * 4 + mi][ni], 0, 0, 0);
        }
        __builtin_amdgcn_s_setprio(0);
        asm volatile("s_waitcnt lgkmcnt(0)" ::: "memory");  // all LDS reads complete
        __builtin_amdgcn_s_barrier();                // buf[cur] free for overwrite
        if (t + 2 < NT) STAGE256(t + 2, cur);        // refill freed buffer
    }
#undef STAGE256

#pragma unroll
    for (int ni = 0; ni < 4; ni++) {
        const int col = bn + wc * 64 + ni * 16 + lane15;
        const float bv = BIAS ? bias[col] : 0.0f;
#pragma unroll
        for (int mi8 = 0; mi8 < 8; mi8++) {
#pragma unroll
            for (int r = 0; r < 4; r++) {
                const int row = bm + wr * 128 + mi8 * 16 + lhi * 4 + r;
                if (row >= ROWS) continue;
                float v = acc[mi8][ni][r] + bv;
                if (ACT == 1) v = silu_f(v);
                if (OUT == 1) ((u16*)Cout)[(size_t)row * Nout + col] = f2b(v);
                else          ((float*)Cout)[((size_t)blockIdx.z * ROWS + row) * Nout + col] = v;
            }
        }
    }
}

// ---------------- m97 128x128 bf16 MFMA GEMM (x_proj / dt_proj) ----------------
// ACT: 0 none, 2 softplus. OUT: 1 bf16 store, 2 f32 atomicAdd.
template <int ACT, bool BIAS, int OUT>
__global__ __launch_bounds__(256) void gemm_mfma(
    const u16* __restrict__ A, const u16* __restrict__ W,
    const float* __restrict__ bias, void* __restrict__ Cout,
    int M, int K, int Nout, int kLen)
{
    __shared__ __align__(16) u16 As[128 * 32];
    __shared__ __align__(16) u16 Bs[128 * 32];
    const int tid = threadIdx.x;
    const int l = tid & 63, w = tid >> 6;
    const int bm = blockIdx.y * 128, bn = blockIdx.x * 128;
    const int kOff = blockIdx.z * kLen;

    const int sr = l >> 2;
    const int sk = (l & 3) * 8;
    const u16* gA = A + (size_t)(bm + w * 16 + sr) * K + kOff + sk;
    const u16* gB = W + (size_t)(bn + w * 16 + sr) * K + kOff + sk;
    u16* lA = As + (w * 16 + sr) * 32 + sk;
    u16* lB = Bs + (w * 16 + sr) * 32 + sk;

    const int lane15 = l & 15, lhi = l >> 4;
    const int wr = w >> 1, wc = w & 1;
    const u16* fA = As + (wr * 64 + lane15) * 32 + lhi * 8;
    const u16* fB = Bs + (wc * 64 + lane15) * 32 + lhi * 8;

    f32x4 acc[4][4] = {};

    for (int kk = 0; kk < kLen; kk += 32) {
        GLD16(gA, lA); GLD16(gA + (size_t)64 * K, lA + 64 * 32);
        GLD16(gB, lB); GLD16(gB + (size_t)64 * K, lB + 64 * 32);
        gA += 32; gB += 32;
        __syncthreads();
        s16x8 af[4], bfr[4];
#pragma unroll
        for (int mi = 0; mi < 4; mi++) af[mi]  = *(const s16x8*)(fA + mi * 16 * 32);
#pragma unroll
        for (int ni = 0; ni < 4; ni++) bfr[ni] = *(const s16x8*)(fB + ni * 16 * 32);
#pragma unroll
        for (int mi = 0; mi < 4; mi++)
#pragma unroll
            for (int ni = 0; ni < 4; ni++)
                acc[mi][ni] = __builtin_amdgcn_mfma_f32_16x16x32_bf16(
                    af[mi], bfr[ni], acc[mi][ni], 0, 0, 0);
        __syncthreads();
    }

#pragma unroll
    for (int ni = 0; ni < 4; ni++) {
        const int col = bn + wc * 64 + ni * 16 + lane15;
        if (col >= Nout) continue;
        const float bv = BIAS ? bias[col] : 0.0f;
#pragma unroll
        for (int mi = 0; mi < 4; mi++) {
#pragma unroll
            for (int r = 0; r < 4; r++) {
                const int row = bm + wr * 64 + mi * 16 + lhi * 4 + r;
                float v = acc[mi][ni][r] + bv;
                if (ACT == 2) v = (v > 20.0f) ? v : log1pf(__expf(v));
                if (OUT == 1) ((u16*)Cout)[(size_t)row * Nout + col] = f2b(v);
                if (OUT == 2) atomicAdd(&((float*)Cout)[(size_t)row * Nout + col], v);
            }
        }
    }
}

// ---------------- classifier layer 1: split-K MFMA with fused f32->bf16 staging ----------------
#define KCH 512
__global__ __launch_bounds__(256) void gemm_cls_mfma(
    const float* __restrict__ A, const float* __restrict__ W,
    float* __restrict__ C)
{
    __shared__ __align__(16) u16 As[128 * 32];
    __shared__ __align__(16) u16 Bs[128 * 32];
    const int tid = threadIdx.x;
    const int l = tid & 63, w = tid >> 6;
    const int bn = blockIdx.x * 128;
    const int k0 = blockIdx.y * KCH;

    const int sr = l >> 2;
    const int sk = (l & 3) * 8;
    const int row = w * 16 + sr;
    const float* gA0 = A + (size_t)row * KCLS + k0 + sk;
    const float* gA1 = gA0 + (size_t)64 * KCLS;
    const float* gB0 = W + (size_t)(bn + row) * KCLS + k0 + sk;
    const float* gB1 = gB0 + (size_t)64 * KCLS;
    u16* lA0 = As + row * 32 + sk;  u16* lA1 = lA0 + 64 * 32;
    u16* lB0 = Bs + row * 32 + sk;  u16* lB1 = lB0 + 64 * 32;

    const int lane15 = l & 15, lhi = l >> 4;
    const int wr = w >> 1, wc = w & 1;
    const u16* fA = As + (wr * 64 + lane15) * 32 + lhi * 8;
    const u16* fB = Bs + (wc * 64 + lane15) * 32 + lhi * 8;

    f32x4 acc[4][4] = {};

    for (int ks = 0; ks < KCH / 32; ks++) {
        float4 a00 = *(const float4*)(gA0);     float4 a01 = *(const float4*)(gA0 + 4);
        float4 a10 = *(const float4*)(gA1);     float4 a11 = *(const float4*)(gA1 + 4);
        float4 b00 = *(const float4*)(gB0);     float4 b01 = *(const float4*)(gB0 + 4);
        float4 b10 = *(const float4*)(gB1);     float4 b11 = *(const float4*)(gB1 + 4);
        gA0 += 32; gA1 += 32; gB0 += 32; gB1 += 32;
        __syncthreads();
        uint4 r;
        r.x = pack2(a00.x, a00.y); r.y = pack2(a00.z, a00.w);
        r.z = pack2(a01.x, a01.y); r.w = pack2(a01.z, a01.w);
        *(uint4*)lA0 = r;
        r.x = pack2(a10.x, a10.y); r.y = pack2(a10.z, a10.w);
        r.z = pack2(a11.x, a11.y); r.w = pack2(a11.z, a11.w);
        *(uint4*)lA1 = r;
        r.x = pack2(b00.x, b00.y); r.y = pack2(b00.z, b00.w);
        r.z = pack2(b01.x, b01.y); r.w = pack2(b01.z, b01.w);
        *(uint4*)lB0 = r;
        r.x = pack2(b10.x, b10.y); r.y = pack2(b10.z, b10.w);
        r.z = pack2(b11.x, b11.y); r.w = pack2(b11.z, b11.w);
        *(uint4*)lB1 = r;
        __syncthreads();
        s16x8 af[4], bfr[4];
#pragma unroll
        for (int mi = 0; mi < 4; mi++) af[mi]  = *(const s16x8*)(fA + mi * 16 * 32);
#pragma unroll
        for (int ni = 0; ni < 4; ni++) bfr[ni] = *(const s16x8*)(fB + ni * 16 * 32);
#pragma unroll
        for (int mi = 0; mi < 4; mi++)
#pragma unroll
            for (int ni = 0; ni < 4; ni++)
                acc[mi][ni] = __builtin_amdgcn_mfma_f32_16x16x32_bf16(
                    af[mi], bfr[ni], acc[mi][ni], 0, 0, 0);
    }

#pragma unroll
    for (int ni = 0; ni < 4; ni++) {
        const int col = bn + wc * 64 + ni * 16 + lane15;
#pragma unroll
        for (int mi = 0; mi < 4; mi++) {
#pragma unroll
            for (int r = 0; r < 4; r++) {
                const int m = wr * 64 + mi * 16 + lhi * 4 + r;
                atomicAdd(&C[(size_t)m * 1024 + col], acc[mi][ni][r]);
            }
        }
    }
}

// ---------------- causal depthwise conv1d (DC=5) + SiLU -> bf16 (bf16 in) ----------------
__global__ __launch_bounds__(256) void conv_silu_kernel(const u16* __restrict__ xz,
                                                        const float* __restrict__ cw,
                                                        const float* __restrict__ cb,
                                                        u16* __restrict__ uc)
{
    const int idx = blockIdx.x * 256 + threadIdx.x;   // over B*L*DI
    const int d  = idx & (DI_ - 1);
    const int bl = idx >> 11;
    const int l  = bl % L_;
    const int b  = bl / L_;
    const u16* u = xz + (size_t)b * L_ * (2 * DI_) + d;
    float acc = cb[d];
#pragma unroll
    for (int k = 0; k < DC_; k++) {
        const int ll = l + k - (DC_ - 1);
        if (ll >= 0) acc = fmaf(b2f(u[(size_t)ll * (2 * DI_)]), cw[d * DC_ + k], acc);
    }
    uc[(size_t)bl * DI_ + d] = f2b(silu_f(acc));
}

// ---------------- extract xdbl[:, 0:64] -> bf16 (dt_proj A operand) ----------------
__global__ __launch_bounds__(256) void dtext_kernel(const float* __restrict__ xdbl,
                                                    u16* __restrict__ dtb)
{
    const int idx = blockIdx.x * 256 + threadIdx.x;   // over ROWS*16
    const int row = idx >> 4, c4 = (idx & 15) * 4;
    float4 v = *(const float4*)(xdbl + (size_t)row * 96 + c4);
    uint2 r;
    r.x = pack2(v.x, v.y); r.y = pack2(v.z, v.w);
    *(uint2*)(dtb + (size_t)row * 64 + c4) = r;
}

// ---------------- selective scan: one thread per (b, d), DS=16 states in regs ----------------
__global__ __launch_bounds__(256) void scan_kernel(const u16* __restrict__ dt,
                                                   const u16* __restrict__ uc,
                                                   const u16* __restrict__ xz,
                                                   const float* __restrict__ xdbl,
                                                   const float* __restrict__ A_log,
                                                   const float* __restrict__ D_ssm,
                                                   u16* __restrict__ y)
{
    const int idx = blockIdx.x * 256 + threadIdx.x;   // over B*DI
    const int d = idx & (DI_ - 1);
    const int b = idx >> 11;
    float A[DS_];
#pragma unroll
    for (int s = 0; s < DS_; s++) A[s] = -__expf(A_log[d * DS_ + s]);
    const float Dv = D_ssm[d];
    float h[DS_] = {};
    for (int l = 0; l < L_; l++) {
        const size_t bl = (size_t)b * L_ + l;
        const float dtv = b2f(dt[bl * DI_ + d]);
        const float uv  = b2f(uc[bl * DI_ + d]);
        const float zv  = b2f(xz[bl * (2 * DI_) + DI_ + d]);
        const float* Bp = xdbl + bl * (DTR_ + 2 * DS_) + DTR_;
        const float* Cp = Bp + DS_;
        float yv = 0.f;
#pragma unroll
        for (int s = 0; s < DS_; s++) {
            h[s] = fmaf(h[s], __expf(dtv * A[s]), dtv * Bp[s] * uv);
            yv = fmaf(h[s], Cp[s], yv);
        }
        yv = fmaf(uv, Dv, yv);
        yv *= silu_f(zv);
        y[bl * DI_ + d] = f2b(yv);
    }
}

// ---------------- classifier layer 2 ----------------
__global__ __launch_bounds__(256) void cls2_kernel(const float* __restrict__ c,
                                                   const float* __restrict__ b1,
                                                   const float* __restrict__ W2,
                                                   const float* __restrict__ b2,
                                                   float* __restrict__ out)
{
    const int b = blockIdx.x;
    float s = 0.f;
    for (int n = threadIdx.x; n < D_; n += 256) {
        float v = c[b * D_ + n] + b1[n];
        v = silu_f(v);
        s = fmaf(v, W2[n], s);
    }
#pragma unroll
    for (int o = 32; o > 0; o >>= 1) s += __shfl_down(s, o, 64);
    __shared__ float red[4];
    const int wid = threadIdx.x >> 6;
    if ((threadIdx.x & 63) == 0) red[wid] = s;
    __syncthreads();
    if (threadIdx.x == 0) out[b] = red[0] + red[1] + red[2] + red[3] + b2[0];
}

extern "C" void kernel_launch(void* const* d_in, const int* in_sizes, int n_in,
                              void* d_out, int out_size, void* d_ws, size_t ws_size,
                              hipStream_t stream)
{
    const float* x         = (const float*)d_in[0];
    const float* n1w       = (const float*)d_in[1];
    const float* n1b       = (const float*)d_in[2];
    const float* in_projW  = (const float*)d_in[3];
    const float* conv_w    = (const float*)d_in[4];
    const float* conv_b    = (const float*)d_in[5];
    const float* x_projW   = (const float*)d_in[6];
    const float* dt_projW  = (const float*)d_in[7];
    const float* dt_projb  = (const float*)d_in[8];
    const float* A_log     = (const float*)d_in[9];
    const float* D_ssm     = (const float*)d_in[10];
    const float* out_projW = (const float*)d_in[11];
    const float* n2w       = (const float*)d_in[12];
    const float* n2b       = (const float*)d_in[13];
    const float* ffn_W1    = (const float*)d_in[14];
    const float* ffn_b1    = (const float*)d_in[15];
    const float* ffn_W2    = (const float*)d_in[16];
    const float* ffn_b2    = (const float*)d_in[17];
    const float* cls_W1    = (const float*)d_in[18];
    const float* cls_b1    = (const float*)d_in[19];
    const float* cls_W2    = (const float*)d_in[20];
    const float* cls_b2    = (const float*)d_in[21];

    // ---- workspace layout (u16 element arithmetic; A-operand buffers padded to MPAD rows) ----
    u16* base   = (u16*)d_ws;
    u16* xz_b   = base;                               // ROWS*4096
    u16* uc_b   = xz_b + (size_t)ROWS * 4096;         // MPAD*2048 (padded: ffn2/x_proj A)
    u16* dt_b   = uc_b + (size_t)MPAD * 2048;         // ROWS*2048
    u16* y_b    = dt_b + (size_t)ROWS * 2048;         // MPAD*2048 (padded: out_proj A)
    u16* h_b    = y_b + (size_t)MPAD * 2048;          // MPAD*1024 (padded: in_proj/ffn1 A)
    float* x2   = (float*)(h_b + (size_t)MPAD * 1024);// ROWS*1024 f32
    float* xdbl = x2 + (size_t)ROWS * 1024;           // ROWS*96 f32
    u16* dtb    = (u16*)(xdbl + (size_t)ROWS * 96);   // ROWS*64
    u16* wbuf   = dtb + (size_t)ROWS * 64;            // WTOT
    float* clsh = (float*)(wbuf + (size_t)WTOT);      // 128*1024 f32
    float* pq   = clsh + (size_t)B_ * D_;             // 4 * ROWS*1024 f32 (split-K partials)

    float* outv = (float*)d_out;    // (B,1)
    float* x3   = outv + B_;        // (B,L,D)

    // 0. all weight conversions
    f2b_all_kernel<<<dim3(5312), dim3(256), 0, stream>>>(
        in_projW, out_projW, ffn_W1, ffn_W2, x_projW, dt_projW, wbuf);
    // 1. LN1 -> bf16
    ln_kernel<<<dim3(ROWS), dim3(256), 0, stream>>>(x, n1w, n1b, h_b);
    // 2. in_proj (256-tile pipelined) -> bf16 xz   (3968 x 4096, K=1024), 256 blocks
    gemm256<0, false, 1><<<dim3(16, 16, 1), dim3(512), 0, stream>>>(
        h_b, wbuf + W_IN, nullptr, xz_b, D_, 2 * DI_, D_);
    // 3. causal conv + SiLU -> bf16
    conv_silu_kernel<<<dim3(ROWS * DI_ / 256), dim3(256), 0, stream>>>(xz_b, conv_w, conv_b, uc_b);
    // 4. x_proj (m97 split-K x16, atomic f32): xdbl = uc @ x_proj_W^T   (3968 x 96, K=2048)
    hipMemsetAsync(xdbl, 0, (size_t)ROWS * 96 * sizeof(float), stream);
    gemm_mfma<0, false, 2><<<dim3(1, 31, 16), dim3(256), 0, stream>>>(
        uc_b, wbuf + W_XP, nullptr, xdbl, ROWS, DI_, DTR_ + 2 * DS_, 128);
    // 5. dt_proj (m97, softplus) -> bf16   (3968 x 2048, K=64)
    dtext_kernel<<<dim3(ROWS * 16 / 256), dim3(256), 0, stream>>>(xdbl, dtb);
    gemm_mfma<2, true, 1><<<dim3(16, 31, 1), dim3(256), 0, stream>>>(
        dtb, wbuf + W_DT, dt_projb, dt_b, ROWS, DTR_, DI_, DTR_);
    // 6. selective scan (+ skip + gate) -> bf16 y
    scan_kernel<<<dim3(B_ * DI_ / 256), dim3(256), 0, stream>>>(
        dt_b, uc_b, xz_b, xdbl, A_log, D_ssm, y_b);
    // 7. out_proj (256-tile pipelined split-K z=4) -> partials   (3968 x 1024, K=2048)
    gemm256<0, false, 3><<<dim3(4, 16, 4), dim3(512), 0, stream>>>(
        y_b, wbuf + W_OUT, nullptr, pq, DI_, D_, 512);
    // 8. fused combine + LN2: x2 = x + Σp, h2 = LN(x2) -> bf16
    ln2_fuse_kernel<<<dim3(ROWS), dim3(256), 0, stream>>>(x, pq, n2w, n2b, x2, h_b);
    // 9. ffn1 (256-tile pipelined) + bias + SiLU -> bf16   (3968 x 2048, K=1024)
    gemm256<1, true, 1><<<dim3(8, 16, 1), dim3(512), 0, stream>>>(
        h_b, wbuf + W_F1, ffn_b1, uc_b, D_, 2 * D_, D_);
    // 10. ffn2 (256-tile pipelined split-K z=4) -> partials   (3968 x 1024, K=2048)
    gemm256<0, false, 3><<<dim3(4, 16, 4), dim3(512), 0, stream>>>(
        uc_b, wbuf + W_F2, nullptr, pq, 2 * D_, D_, 512);
    // 11. combine: x3 = x2 + Σq + b2 -> d_out
    add4_bias_kernel<<<dim3(ROWS * D_ / 4 / 256), dim3(256), 0, stream>>>(
        x2, pq, ffn_b2, x3);
    // 12. classifier layer 1: split-K MFMA, fused f32->bf16 staging
    hipMemsetAsync(clsh, 0, (size_t)B_ * D_ * sizeof(float), stream);
    gemm_cls_mfma<<<dim3(1024 / 128, KCLS / KCH), dim3(256), 0, stream>>>(x3, cls_W1, clsh);
    // 13. classifier layer 2
    cls2_kernel<<<dim3(B_), dim3(256), 0, stream>>>(clsh, cls_b1, cls_W2, cls_b2, outv);
}

// Round 9
// 392.129 us; speedup vs baseline: 1.1321x; 1.1321x over previous
//
#include <hip/hip_runtime.h>
#include <cstddef>
#include <cstdint>

#define B_   128
#define L_   31
#define D_   1024
#define DI_  2048
#define DS_  16
#define DC_  5
#define DTR_ 64
#define ROWS (B_ * L_)   // 3968
#define KCLS (L_ * D_)   // 31744

// weight-buffer offsets (u16 elements)
#define W_IN  0          // 4096x1024
#define W_OUT 4194304    // 1024x2048
#define W_F1  6291456    // 2048x1024
#define W_F2  8388608    // 1024x2048
#define W_XP  10485760   // 128x2048 (rows 96..127 zero)
#define W_DT  10747904   // 2048x64
#define WTOT  10878976

typedef unsigned short u16;
typedef __attribute__((ext_vector_type(8))) short s16x8;
typedef __attribute__((ext_vector_type(4))) float f32x4;

__device__ __forceinline__ float silu_f(float x) { return x / (1.0f + __expf(-x)); }

__device__ __forceinline__ u16 f2b(float f) {
    union { float f; uint32_t u; } c; c.f = f;
    uint32_t u = c.u + 0x7FFF + ((c.u >> 16) & 1);
    return (u16)(u >> 16);
}
__device__ __forceinline__ float b2f(u16 b) {
    union { uint32_t u; float f; } c; c.u = ((uint32_t)b) << 16;
    return c.f;
}
__device__ __forceinline__ uint32_t pack2(float lo, float hi) {
    return (uint32_t)f2b(lo) | ((uint32_t)f2b(hi) << 16);
}
__device__ __forceinline__ void cvt8(const float* __restrict__ s, u16* __restrict__ d) {
    const float4* p = (const float4*)s;
    float4 a = p[0], b = p[1];
    uint4 r;
    r.x = pack2(a.x, a.y); r.y = pack2(a.z, a.w);
    r.z = pack2(b.x, b.y); r.w = pack2(b.z, b.w);
    *(uint4*)d = r;
}

#define GLD16(g, s) __builtin_amdgcn_global_load_lds( \
    (const __attribute__((address_space(1))) void*)(g), \
    (__attribute__((address_space(3))) void*)(s), 16, 0, 0)

// ---------------- all-weights fp32 -> bf16 (single launch) ----------------
__global__ __launch_bounds__(256) void f2b_all_kernel(
    const float* __restrict__ inW, const float* __restrict__ outW,
    const float* __restrict__ f1W, const float* __restrict__ f2W,
    const float* __restrict__ xpW, const float* __restrict__ dtW,
    u16* __restrict__ wbuf)
{
    int g = blockIdx.x * 256 + threadIdx.x;
    if (g < 524288) { cvt8(inW + (size_t)g * 8, wbuf + W_IN + (size_t)g * 8); return; }
    g -= 524288;
    if (g < 262144) { cvt8(outW + (size_t)g * 8, wbuf + W_OUT + (size_t)g * 8); return; }
    g -= 262144;
    if (g < 262144) { cvt8(f1W + (size_t)g * 8, wbuf + W_F1 + (size_t)g * 8); return; }
    g -= 262144;
    if (g < 262144) { cvt8(f2W + (size_t)g * 8, wbuf + W_F2 + (size_t)g * 8); return; }
    g -= 262144;
    if (g < 32768) {   // x_proj, padded 96 -> 128 rows
        const int row = g >> 8, col8 = (g & 255) * 8;
        u16* d = wbuf + W_XP + (size_t)row * 2048 + col8;
        if (row < 96) cvt8(xpW + (size_t)row * 2048 + col8, d);
        else *(uint4*)d = make_uint4(0, 0, 0, 0);
        return;
    }
    g -= 32768;
    if (g < 16384) cvt8(dtW + (size_t)g * 8, wbuf + W_DT + (size_t)g * 8);
}

// ---------------- LayerNorm (one block per row, D=1024) -> bf16 out ----------------
__global__ __launch_bounds__(256) void ln_kernel(const float* __restrict__ x,
                                                 const float* __restrict__ w,
                                                 const float* __restrict__ b,
                                                 u16* __restrict__ y)
{
    const int row = blockIdx.x;
    const float* xr = x + (size_t)row * D_;
    float v[4];
    float sum = 0.f, sq = 0.f;
#pragma unroll
    for (int i = 0; i < 4; i++) {
        v[i] = xr[threadIdx.x + i * 256];
        sum += v[i];
        sq  += v[i] * v[i];
    }
#pragma unroll
    for (int o = 32; o > 0; o >>= 1) {
        sum += __shfl_down(sum, o, 64);
        sq  += __shfl_down(sq, o, 64);
    }
    __shared__ float red[8];
    const int wid = threadIdx.x >> 6;
    if ((threadIdx.x & 63) == 0) { red[wid] = sum; red[4 + wid] = sq; }
    __syncthreads();
    sum = red[0] + red[1] + red[2] + red[3];
    sq  = red[4] + red[5] + red[6] + red[7];
    const float mean = sum * (1.0f / D_);
    const float var  = sq * (1.0f / D_) - mean * mean;
    const float rstd = rsqrtf(var + 1e-5f);
    u16* yr = y + (size_t)row * D_;
#pragma unroll
    for (int i = 0; i < 4; i++) {
        const int c = threadIdx.x + i * 256;
        yr[c] = f2b((v[i] - mean) * rstd * w[c] + b[c]);
    }
}

// ---------------- fused: x2 = x + p0 + p1; h2 = LN(x2) -> bf16 ----------------
__global__ __launch_bounds__(256) void ln2_fuse_kernel(const float* __restrict__ x,
                                                       const float* __restrict__ p0,
                                                       const float* __restrict__ p1,
                                                       const float* __restrict__ w,
                                                       const float* __restrict__ b,
                                                       float* __restrict__ x2,
                                                       u16* __restrict__ y)
{
    const int row = blockIdx.x;
    const size_t base = (size_t)row * D_;
    float v[4];
    float sum = 0.f, sq = 0.f;
#pragma unroll
    for (int i = 0; i < 4; i++) {
        const int c = threadIdx.x + i * 256;
        const float s = x[base + c] + p0[base + c] + p1[base + c];
        x2[base + c] = s;
        v[i] = s;
        sum += s;
        sq  += s * s;
    }
#pragma unroll
    for (int o = 32; o > 0; o >>= 1) {
        sum += __shfl_down(sum, o, 64);
        sq  += __shfl_down(sq, o, 64);
    }
    __shared__ float red[8];
    const int wid = threadIdx.x >> 6;
    if ((threadIdx.x & 63) == 0) { red[wid] = sum; red[4 + wid] = sq; }
    __syncthreads();
    sum = red[0] + red[1] + red[2] + red[3];
    sq  = red[4] + red[5] + red[6] + red[7];
    const float mean = sum * (1.0f / D_);
    const float var  = sq * (1.0f / D_) - mean * mean;
    const float rstd = rsqrtf(var + 1e-5f);
    u16* yr = y + base;
#pragma unroll
    for (int i = 0; i < 4; i++) {
        const int c = threadIdx.x + i * 256;
        yr[c] = f2b((v[i] - mean) * rstd * w[c] + b[c]);
    }
}

// ---------------- x3 = x2 + q0 + q1 + b2 (vectorized) ----------------
__global__ __launch_bounds__(256) void add3_bias_kernel(const float* __restrict__ x2,
                                                        const float* __restrict__ q0,
                                                        const float* __restrict__ q1,
                                                        const float* __restrict__ b2,
                                                        float* __restrict__ x3)
{
    const int i = blockIdx.x * 256 + threadIdx.x;   // float4 index over ROWS*1024/4
    float4 a  = ((const float4*)x2)[i];
    float4 c0 = ((const float4*)q0)[i];
    float4 c1 = ((const float4*)q1)[i];
    float4 bb = ((const float4*)b2)[i & 255];
    float4 r;
    r.x = a.x + c0.x + c1.x + bb.x;
    r.y = a.y + c0.y + c1.y + bb.y;
    r.z = a.z + c0.z + c1.z + bb.z;
    r.w = a.w + c0.w + c1.w + bb.w;
    ((float4*)x3)[i] = r;
}

// ======== 128x128-tile bf16 MFMA GEMM, BK=64, 4 waves, XOR-swizzled LDS ========
// m97 skeleton (proven 2-barrier loop) with BK 32->64: halves barrier-drain
// frequency; LDS 32 KB keeps ~3 blocks/CU. Both-sides swizzle (rule #21, HW-
// verified in R7): linear LDS dest, global source granule sg^(srow&7), fragment
// read granule (ks*4+lhi)^(lane15&7) -> 2-way max bank aliasing (free, m136).
// ACT: 0 none, 1 silu. OUT: 1 bf16 store, 3 f32 partial (z-indexed, M=ROWS).
template <int ACT, bool BIAS, int OUT>
__global__ __launch_bounds__(256) void gemm128_bk64(
    const u16* __restrict__ A, const u16* __restrict__ W,
    const float* __restrict__ bias, void* __restrict__ Cout,
    int M, int K, int Nout, int kLen)
{
    __shared__ __align__(16) u16 As[128 * 64];   // 16 KB
    __shared__ __align__(16) u16 Bs[128 * 64];   // 16 KB
    const int tid = threadIdx.x;
    const int l = tid & 63, w = tid >> 6;
    const int bm = blockIdx.y * 128, bn = blockIdx.x * 128;
    const int kOff = blockIdx.z * kLen;

    // staging: thread = 16B; chunk c covers rows [c*32, c*32+32)
    const int srow = tid >> 3;                   // 0..31
    const int sg   = tid & 7;                    // LDS granule slot (linear)
    const int sgx  = sg ^ (srow & 7);            // swizzled SOURCE granule
    const u16* gA = A + (size_t)(bm + srow) * K + kOff + sgx * 8;
    const u16* gB = W + (size_t)(bn + srow) * K + kOff + sgx * 8;
    const int soff = srow * 64 + sg * 8;         // == tid*8 (lane-linear)

    const int lane15 = l & 15, lhi = l >> 4;
    const int key = lane15 & 7;
    const int wr = w >> 1, wc = w & 1;
    const u16* fArow = As + (wr * 64 + lane15) * 64;
    const u16* fBrow = Bs + (wc * 64 + lane15) * 64;

    f32x4 acc[4][4] = {};

    for (int kk = 0; kk < kLen; kk += 64) {
#pragma unroll
        for (int c = 0; c < 4; c++) {
            GLD16(gA + (size_t)c * 32 * K, As + c * 2048 + soff);
            GLD16(gB + (size_t)c * 32 * K, Bs + c * 2048 + soff);
        }
        gA += 64; gB += 64;
        __syncthreads();                         // tile visible (vmcnt0 drain)
#pragma unroll
        for (int ks = 0; ks < 2; ks++) {
            const int gsel = ((ks * 4 + lhi) ^ key) * 8;
            s16x8 af[4], bfr[4];
#pragma unroll
            for (int mi = 0; mi < 4; mi++) af[mi]  = *(const s16x8*)(fArow + mi * 16 * 64 + gsel);
#pragma unroll
            for (int ni = 0; ni < 4; ni++) bfr[ni] = *(const s16x8*)(fBrow + ni * 16 * 64 + gsel);
#pragma unroll
            for (int mi = 0; mi < 4; mi++)
#pragma unroll
                for (int ni = 0; ni < 4; ni++)
                    acc[mi][ni] = __builtin_amdgcn_mfma_f32_16x16x32_bf16(
                        af[mi], bfr[ni], acc[mi][ni], 0, 0, 0);
        }
        __syncthreads();                         // reads done before re-stage
    }

#pragma unroll
    for (int ni = 0; ni < 4; ni++) {
        const int col = bn + wc * 64 + ni * 16 + lane15;
        const float bv = BIAS ? bias[col] : 0.0f;
#pragma unroll
        for (int mi = 0; mi < 4; mi++) {
#pragma unroll
            for (int r = 0; r < 4; r++) {
                const int row = bm + wr * 64 + mi * 16 + lhi * 4 + r;
                float v = acc[mi][ni][r] + bv;
                if (ACT == 1) v = silu_f(v);
                if (OUT == 1) ((u16*)Cout)[(size_t)row * Nout + col] = f2b(v);
                else          ((float*)Cout)[((size_t)blockIdx.z * M + row) * Nout + col] = v;
            }
        }
    }
}

// ---------------- m97 128x128 bf16 MFMA GEMM, BK=32 (x_proj / dt_proj) ----------------
// ACT: 0 none, 2 softplus. OUT: 1 bf16 store, 2 f32 atomicAdd.
template <int ACT, bool BIAS, int OUT>
__global__ __launch_bounds__(256) void gemm_mfma(
    const u16* __restrict__ A, const u16* __restrict__ W,
    const float* __restrict__ bias, void* __restrict__ Cout,
    int M, int K, int Nout, int kLen)
{
    __shared__ __align__(16) u16 As[128 * 32];
    __shared__ __align__(16) u16 Bs[128 * 32];
    const int tid = threadIdx.x;
    const int l = tid & 63, w = tid >> 6;
    const int bm = blockIdx.y * 128, bn = blockIdx.x * 128;
    const int kOff = blockIdx.z * kLen;

    const int sr = l >> 2;
    const int sk = (l & 3) * 8;
    const u16* gA = A + (size_t)(bm + w * 16 + sr) * K + kOff + sk;
    const u16* gB = W + (size_t)(bn + w * 16 + sr) * K + kOff + sk;
    u16* lA = As + (w * 16 + sr) * 32 + sk;
    u16* lB = Bs + (w * 16 + sr) * 32 + sk;

    const int lane15 = l & 15, lhi = l >> 4;
    const int wr = w >> 1, wc = w & 1;
    const u16* fA = As + (wr * 64 + lane15) * 32 + lhi * 8;
    const u16* fB = Bs + (wc * 64 + lane15) * 32 + lhi * 8;

    f32x4 acc[4][4] = {};

    for (int kk = 0; kk < kLen; kk += 32) {
        GLD16(gA, lA); GLD16(gA + (size_t)64 * K, lA + 64 * 32);
        GLD16(gB, lB); GLD16(gB + (size_t)64 * K, lB + 64 * 32);
        gA += 32; gB += 32;
        __syncthreads();
        s16x8 af[4], bfr[4];
#pragma unroll
        for (int mi = 0; mi < 4; mi++) af[mi]  = *(const s16x8*)(fA + mi * 16 * 32);
#pragma unroll
        for (int ni = 0; ni < 4; ni++) bfr[ni] = *(const s16x8*)(fB + ni * 16 * 32);
#pragma unroll
        for (int mi = 0; mi < 4; mi++)
#pragma unroll
            for (int ni = 0; ni < 4; ni++)
                acc[mi][ni] = __builtin_amdgcn_mfma_f32_16x16x32_bf16(
                    af[mi], bfr[ni], acc[mi][ni], 0, 0, 0);
        __syncthreads();
    }

#pragma unroll
    for (int ni = 0; ni < 4; ni++) {
        const int col = bn + wc * 64 + ni * 16 + lane15;
        if (col >= Nout) continue;
        const float bv = BIAS ? bias[col] : 0.0f;
#pragma unroll
        for (int mi = 0; mi < 4; mi++) {
#pragma unroll
            for (int r = 0; r < 4; r++) {
                const int row = bm + wr * 64 + mi * 16 + lhi * 4 + r;
                float v = acc[mi][ni][r] + bv;
                if (ACT == 2) v = (v > 20.0f) ? v : log1pf(__expf(v));
                if (OUT == 1) ((u16*)Cout)[(size_t)row * Nout + col] = f2b(v);
                if (OUT == 2) atomicAdd(&((float*)Cout)[(size_t)row * Nout + col], v);
            }
        }
    }
}

// ---------------- classifier layer 1: split-K MFMA with fused f32->bf16 staging ----------------
#define KCH 512
__global__ __launch_bounds__(256) void gemm_cls_mfma(
    const float* __restrict__ A, const float* __restrict__ W,
    float* __restrict__ C)
{
    __shared__ __align__(16) u16 As[128 * 32];
    __shared__ __align__(16) u16 Bs[128 * 32];
    const int tid = threadIdx.x;
    const int l = tid & 63, w = tid >> 6;
    const int bn = blockIdx.x * 128;
    const int k0 = blockIdx.y * KCH;

    const int sr = l >> 2;
    const int sk = (l & 3) * 8;
    const int row = w * 16 + sr;
    const float* gA0 = A + (size_t)row * KCLS + k0 + sk;
    const float* gA1 = gA0 + (size_t)64 * KCLS;
    const float* gB0 = W + (size_t)(bn + row) * KCLS + k0 + sk;
    const float* gB1 = gB0 + (size_t)64 * KCLS;
    u16* lA0 = As + row * 32 + sk;  u16* lA1 = lA0 + 64 * 32;
    u16* lB0 = Bs + row * 32 + sk;  u16* lB1 = lB0 + 64 * 32;

    const int lane15 = l & 15, lhi = l >> 4;
    const int wr = w >> 1, wc = w & 1;
    const u16* fA = As + (wr * 64 + lane15) * 32 + lhi * 8;
    const u16* fB = Bs + (wc * 64 + lane15) * 32 + lhi * 8;

    f32x4 acc[4][4] = {};

    for (int ks = 0; ks < KCH / 32; ks++) {
        float4 a00 = *(const float4*)(gA0);     float4 a01 = *(const float4*)(gA0 + 4);
        float4 a10 = *(const float4*)(gA1);     float4 a11 = *(const float4*)(gA1 + 4);
        float4 b00 = *(const float4*)(gB0);     float4 b01 = *(const float4*)(gB0 + 4);
        float4 b10 = *(const float4*)(gB1);     float4 b11 = *(const float4*)(gB1 + 4);
        gA0 += 32; gA1 += 32; gB0 += 32; gB1 += 32;
        __syncthreads();
        uint4 r;
        r.x = pack2(a00.x, a00.y); r.y = pack2(a00.z, a00.w);
        r.z = pack2(a01.x, a01.y); r.w = pack2(a01.z, a01.w);
        *(uint4*)lA0 = r;
        r.x = pack2(a10.x, a10.y); r.y = pack2(a10.z, a10.w);
        r.z = pack2(a11.x, a11.y); r.w = pack2(a11.z, a11.w);
        *(uint4*)lA1 = r;
        r.x = pack2(b00.x, b00.y); r.y = pack2(b00.z, b00.w);
        r.z = pack2(b01.x, b01.y); r.w = pack2(b01.z, b01.w);
        *(uint4*)lB0 = r;
        r.x = pack2(b10.x, b10.y); r.y = pack2(b10.z, b10.w);
        r.z = pack2(b11.x, b11.y); r.w = pack2(b11.z, b11.w);
        *(uint4*)lB1 = r;
        __syncthreads();
        s16x8 af[4], bfr[4];
#pragma unroll
        for (int mi = 0; mi < 4; mi++) af[mi]  = *(const s16x8*)(fA + mi * 16 * 32);
#pragma unroll
        for (int ni = 0; ni < 4; ni++) bfr[ni] = *(const s16x8*)(fB + ni * 16 * 32);
#pragma unroll
        for (int mi = 0; mi < 4; mi++)
#pragma unroll
            for (int ni = 0; ni < 4; ni++)
                acc[mi][ni] = __builtin_amdgcn_mfma_f32_16x16x32_bf16(
                    af[mi], bfr[ni], acc[mi][ni], 0, 0, 0);
    }

#pragma unroll
    for (int ni = 0; ni < 4; ni++) {
        const int col = bn + wc * 64 + ni * 16 + lane15;
#pragma unroll
        for (int mi = 0; mi < 4; mi++) {
#pragma unroll
            for (int r = 0; r < 4; r++) {
                const int m = wr * 64 + mi * 16 + lhi * 4 + r;
                atomicAdd(&C[(size_t)m * 1024 + col], acc[mi][ni][r]);
            }
        }
    }
}

// ---------------- causal depthwise conv1d (DC=5) + SiLU -> bf16 (bf16 in) ----------------
__global__ __launch_bounds__(256) void conv_silu_kernel(const u16* __restrict__ xz,
                                                        const float* __restrict__ cw,
                                                        const float* __restrict__ cb,
                                                        u16* __restrict__ uc)
{
    const int idx = blockIdx.x * 256 + threadIdx.x;   // over B*L*DI
    const int d  = idx & (DI_ - 1);
    const int bl = idx >> 11;
    const int l  = bl % L_;
    const int b  = bl / L_;
    const u16* u = xz + (size_t)b * L_ * (2 * DI_) + d;
    float acc = cb[d];
#pragma unroll
    for (int k = 0; k < DC_; k++) {
        const int ll = l + k - (DC_ - 1);
        if (ll >= 0) acc = fmaf(b2f(u[(size_t)ll * (2 * DI_)]), cw[d * DC_ + k], acc);
    }
    uc[(size_t)bl * DI_ + d] = f2b(silu_f(acc));
}

// ---------------- extract xdbl[:, 0:64] -> bf16 (dt_proj A operand) ----------------
__global__ __launch_bounds__(256) void dtext_kernel(const float* __restrict__ xdbl,
                                                    u16* __restrict__ dtb)
{
    const int idx = blockIdx.x * 256 + threadIdx.x;   // over ROWS*16
    const int row = idx >> 4, c4 = (idx & 15) * 4;
    float4 v = *(const float4*)(xdbl + (size_t)row * 96 + c4);
    uint2 r;
    r.x = pack2(v.x, v.y); r.y = pack2(v.z, v.w);
    *(uint2*)(dtb + (size_t)row * 64 + c4) = r;
}

// ---------------- selective scan: one thread per (b, d), DS=16 states in regs ----------------
__global__ __launch_bounds__(256) void scan_kernel(const u16* __restrict__ dt,
                                                   const u16* __restrict__ uc,
                                                   const u16* __restrict__ xz,
                                                   const float* __restrict__ xdbl,
                                                   const float* __restrict__ A_log,
                                                   const float* __restrict__ D_ssm,
                                                   u16* __restrict__ y)
{
    const int idx = blockIdx.x * 256 + threadIdx.x;   // over B*DI
    const int d = idx & (DI_ - 1);
    const int b = idx >> 11;
    float A[DS_];
#pragma unroll
    for (int s = 0; s < DS_; s++) A[s] = -__expf(A_log[d * DS_ + s]);
    const float Dv = D_ssm[d];
    float h[DS_] = {};
    for (int l = 0; l < L_; l++) {
        const size_t bl = (size_t)b * L_ + l;
        const float dtv = b2f(dt[bl * DI_ + d]);
        const float uv  = b2f(uc[bl * DI_ + d]);
        const float zv  = b2f(xz[bl * (2 * DI_) + DI_ + d]);
        const float* Bp = xdbl + bl * (DTR_ + 2 * DS_) + DTR_;
        const float* Cp = Bp + DS_;
        float yv = 0.f;
#pragma unroll
        for (int s = 0; s < DS_; s++) {
            h[s] = fmaf(h[s], __expf(dtv * A[s]), dtv * Bp[s] * uv);
            yv = fmaf(h[s], Cp[s], yv);
        }
        yv = fmaf(uv, Dv, yv);
        yv *= silu_f(zv);
        y[bl * DI_ + d] = f2b(yv);
    }
}

// ---------------- classifier layer 2 ----------------
__global__ __launch_bounds__(256) void cls2_kernel(const float* __restrict__ c,
                                                   const float* __restrict__ b1,
                                                   const float* __restrict__ W2,
                                                   const float* __restrict__ b2,
                                                   float* __restrict__ out)
{
    const int b = blockIdx.x;
    float s = 0.f;
    for (int n = threadIdx.x; n < D_; n += 256) {
        float v = c[b * D_ + n] + b1[n];
        v = silu_f(v);
        s = fmaf(v, W2[n], s);
    }
#pragma unroll
    for (int o = 32; o > 0; o >>= 1) s += __shfl_down(s, o, 64);
    __shared__ float red[4];
    const int wid = threadIdx.x >> 6;
    if ((threadIdx.x & 63) == 0) red[wid] = s;
    __syncthreads();
    if (threadIdx.x == 0) out[b] = red[0] + red[1] + red[2] + red[3] + b2[0];
}

extern "C" void kernel_launch(void* const* d_in, const int* in_sizes, int n_in,
                              void* d_out, int out_size, void* d_ws, size_t ws_size,
                              hipStream_t stream)
{
    const float* x         = (const float*)d_in[0];
    const float* n1w       = (const float*)d_in[1];
    const float* n1b       = (const float*)d_in[2];
    const float* in_projW  = (const float*)d_in[3];
    const float* conv_w    = (const float*)d_in[4];
    const float* conv_b    = (const float*)d_in[5];
    const float* x_projW   = (const float*)d_in[6];
    const float* dt_projW  = (const float*)d_in[7];
    const float* dt_projb  = (const float*)d_in[8];
    const float* A_log     = (const float*)d_in[9];
    const float* D_ssm     = (const float*)d_in[10];
    const float* out_projW = (const float*)d_in[11];
    const float* n2w       = (const float*)d_in[12];
    const float* n2b       = (const float*)d_in[13];
    const float* ffn_W1    = (const float*)d_in[14];
    const float* ffn_b1    = (const float*)d_in[15];
    const float* ffn_W2    = (const float*)d_in[16];
    const float* ffn_b2    = (const float*)d_in[17];
    const float* cls_W1    = (const float*)d_in[18];
    const float* cls_b1    = (const float*)d_in[19];
    const float* cls_W2    = (const float*)d_in[20];
    const float* cls_b2    = (const float*)d_in[21];

    // ---- workspace layout (R5 layout) ----
    u16* base   = (u16*)d_ws;
    u16* xz_b   = base;                               // ROWS*4096
    u16* uc_b   = xz_b + (size_t)ROWS * 4096;         // ROWS*2048
    u16* dt_b   = uc_b + (size_t)ROWS * 2048;         // ROWS*2048
    u16* y_b    = dt_b + (size_t)ROWS * 2048;         // ROWS*2048
    u16* h_b    = y_b + (size_t)ROWS * 2048;          // ROWS*1024
    float* x2   = (float*)(h_b + (size_t)ROWS * 1024);// ROWS*1024 f32
    float* xdbl = x2 + (size_t)ROWS * 1024;           // ROWS*96 f32
    u16* dtb    = (u16*)(xdbl + (size_t)ROWS * 96);   // ROWS*64
    u16* wbuf   = dtb + (size_t)ROWS * 64;            // WTOT
    float* clsh = (float*)(wbuf + (size_t)WTOT);      // 128*1024 f32
    float* pq   = clsh + (size_t)B_ * D_;             // 2 * ROWS*1024 f32 (split-K partials)

    float* outv = (float*)d_out;    // (B,1)
    float* x3   = outv + B_;        // (B,L,D)

    // 0. all weight conversions
    f2b_all_kernel<<<dim3(5312), dim3(256), 0, stream>>>(
        in_projW, out_projW, ffn_W1, ffn_W2, x_projW, dt_projW, wbuf);
    // 1. LN1 -> bf16
    ln_kernel<<<dim3(ROWS), dim3(256), 0, stream>>>(x, n1w, n1b, h_b);
    // 2. in_proj (BK=64 swz) -> bf16 xz   (3968 x 4096, K=1024), 992 blocks
    gemm128_bk64<0, false, 1><<<dim3(32, 31, 1), dim3(256), 0, stream>>>(
        h_b, wbuf + W_IN, nullptr, xz_b, ROWS, D_, 2 * DI_, D_);
    // 3. causal conv + SiLU -> bf16
    conv_silu_kernel<<<dim3(ROWS * DI_ / 256), dim3(256), 0, stream>>>(xz_b, conv_w, conv_b, uc_b);
    // 4. x_proj (m97 split-K x16, atomic f32): xdbl = uc @ x_proj_W^T   (3968 x 96, K=2048)
    hipMemsetAsync(xdbl, 0, (size_t)ROWS * 96 * sizeof(float), stream);
    gemm_mfma<0, false, 2><<<dim3(1, 31, 16), dim3(256), 0, stream>>>(
        uc_b, wbuf + W_XP, nullptr, xdbl, ROWS, DI_, DTR_ + 2 * DS_, 128);
    // 5. dt_proj (m97, softplus) -> bf16   (3968 x 2048, K=64)
    dtext_kernel<<<dim3(ROWS * 16 / 256), dim3(256), 0, stream>>>(xdbl, dtb);
    gemm_mfma<2, true, 1><<<dim3(16, 31, 1), dim3(256), 0, stream>>>(
        dtb, wbuf + W_DT, dt_projb, dt_b, ROWS, DTR_, DI_, DTR_);
    // 6. selective scan (+ skip + gate) -> bf16 y
    scan_kernel<<<dim3(B_ * DI_ / 256), dim3(256), 0, stream>>>(
        dt_b, uc_b, xz_b, xdbl, A_log, D_ssm, y_b);
    // 7. out_proj (BK=64 swz, split-K z=2) -> partials p0,p1   (3968 x 1024, K=2048)
    gemm128_bk64<0, false, 3><<<dim3(8, 31, 2), dim3(256), 0, stream>>>(
        y_b, wbuf + W_OUT, nullptr, pq, ROWS, DI_, D_, 1024);
    // 8. fused combine + LN2: x2 = x + p0 + p1, h2 = LN(x2) -> bf16
    ln2_fuse_kernel<<<dim3(ROWS), dim3(256), 0, stream>>>(
        x, pq, pq + (size_t)ROWS * D_, n2w, n2b, x2, h_b);
    // 9. ffn1 (BK=64 swz) + bias + SiLU -> bf16   (3968 x 2048, K=1024), 496 blocks
    gemm128_bk64<1, true, 1><<<dim3(16, 31, 1), dim3(256), 0, stream>>>(
        h_b, wbuf + W_F1, ffn_b1, uc_b, ROWS, D_, 2 * D_, D_);
    // 10. ffn2 (BK=64 swz, split-K z=2) -> partials q0,q1   (3968 x 1024, K=2048)
    gemm128_bk64<0, false, 3><<<dim3(8, 31, 2), dim3(256), 0, stream>>>(
        uc_b, wbuf + W_F2, nullptr, pq, ROWS, 2 * D_, D_, 1024);
    // 11. combine: x3 = x2 + q0 + q1 + b2 -> d_out
    add3_bias_kernel<<<dim3(ROWS * D_ / 4 / 256), dim3(256), 0, stream>>>(
        x2, pq, pq + (size_t)ROWS * D_, ffn_b2, x3);
    // 12. classifier layer 1: split-K MFMA, fused f32->bf16 staging
    hipMemsetAsync(clsh, 0, (size_t)B_ * D_ * sizeof(float), stream);
    gemm_cls_mfma<<<dim3(1024 / 128, KCLS / KCH), dim3(256), 0, stream>>>(x3, cls_W1, clsh);
    // 13. classifier layer 2
    cls2_kernel<<<dim3(B_), dim3(256), 0, stream>>>(clsh, cls_b1, cls_W2, cls_b2, outv);
}